// Round 1
// baseline (316.845 us; speedup 1.0000x reference)
//
#include <hip/hip_runtime.h>
#include <hip/hip_bf16.h>
#include <math.h>

#define V_N   6890
#define N_PTS 16384
#define D_IN  700
#define D_HID 256
#define D_OUT 283
#define NCHUNK 8
#define CHUNK  862   // ceil(6890/8)

// ws layout (units: floats; all offsets 16B-aligned)
#define RINV_OFF 0                    // V*9 -> 62010 (pad 62016)
#define KK_OFF   62016                // V   -> 6890  (pad 6912)
#define KNN_OFF  68928                // N ints -> 16384
#define PD_OFF   85312                // N*8 doubles = 262144 floats
#define PI_OFF   347456               // N*8 ints   = 131072
#define X_OFF    478528               // N*700 = 11468800
#define H1_OFF   11947328             // N*256 = 4194304
#define H2_OFF   16141632             // N*256 = 4194304
// end: 20335936 floats = ~81.3 MB

// ---------------- prep: per-vertex inv(4x4)[:3,:3] + |k|^2 ----------------
__global__ __launch_bounds__(256) void prep_kernel(
    const float* __restrict__ trans, const float* __restrict__ keyp,
    float* __restrict__ rinv, float* __restrict__ kk2)
{
    int v = blockIdx.x * 256 + threadIdx.x;
    if (v >= V_N) return;
    float m[16];
#pragma unroll
    for (int i = 0; i < 16; ++i) m[i] = trans[i * V_N + v];

    float i0  =  m[5]*m[10]*m[15] - m[5]*m[11]*m[14] - m[9]*m[6]*m[15] + m[9]*m[7]*m[14] + m[13]*m[6]*m[11] - m[13]*m[7]*m[10];
    float i4  = -m[4]*m[10]*m[15] + m[4]*m[11]*m[14] + m[8]*m[6]*m[15] - m[8]*m[7]*m[14] - m[12]*m[6]*m[11] + m[12]*m[7]*m[10];
    float i8  =  m[4]*m[9]*m[15]  - m[4]*m[11]*m[13] - m[8]*m[5]*m[15] + m[8]*m[7]*m[13] + m[12]*m[5]*m[11] - m[12]*m[7]*m[9];
    float i12 = -m[4]*m[9]*m[14]  + m[4]*m[10]*m[13] + m[8]*m[5]*m[14] - m[8]*m[6]*m[13] - m[12]*m[5]*m[10] + m[12]*m[6]*m[9];
    float i1  = -m[1]*m[10]*m[15] + m[1]*m[11]*m[14] + m[9]*m[2]*m[15] - m[9]*m[3]*m[14] - m[13]*m[2]*m[11] + m[13]*m[3]*m[10];
    float i5  =  m[0]*m[10]*m[15] - m[0]*m[11]*m[14] - m[8]*m[2]*m[15] + m[8]*m[3]*m[14] + m[12]*m[2]*m[11] - m[12]*m[3]*m[10];
    float i9  = -m[0]*m[9]*m[15]  + m[0]*m[11]*m[13] + m[8]*m[1]*m[15] - m[8]*m[3]*m[13] - m[12]*m[1]*m[11] + m[12]*m[3]*m[9];
    float i2  =  m[1]*m[6]*m[15]  - m[1]*m[7]*m[14]  - m[5]*m[2]*m[15] + m[5]*m[3]*m[14] + m[13]*m[2]*m[7]  - m[13]*m[3]*m[6];
    float i6  = -m[0]*m[6]*m[15]  + m[0]*m[7]*m[14]  + m[4]*m[2]*m[15] - m[4]*m[3]*m[14] - m[12]*m[2]*m[7]  + m[12]*m[3]*m[6];
    float i10 =  m[0]*m[5]*m[15]  - m[0]*m[7]*m[13]  - m[4]*m[1]*m[15] + m[4]*m[3]*m[13] + m[12]*m[1]*m[7]  - m[12]*m[3]*m[5];

    float det = m[0]*i0 + m[1]*i4 + m[2]*i8 + m[3]*i12;
    float id = 1.0f / det;
    rinv[v*9+0] = i0*id;  rinv[v*9+1] = i1*id;  rinv[v*9+2] = i2*id;
    rinv[v*9+3] = i4*id;  rinv[v*9+4] = i5*id;  rinv[v*9+5] = i6*id;
    rinv[v*9+6] = i8*id;  rinv[v*9+7] = i9*id;  rinv[v*9+8] = i10*id;

    float kx = keyp[v*3], ky = keyp[v*3+1], kz = keyp[v*3+2];
    kk2[v] = kx*kx + ky*ky + kz*kz;
}

// ---------------- KNN: partial argmin over a V-chunk (fp64 distances) ----------------
__global__ __launch_bounds__(256) void knn_part_kernel(
    const float* __restrict__ pts, const float* __restrict__ keyp,
    double* __restrict__ pd, int* __restrict__ pi)
{
    __shared__ float sx[256], sy[256], sz[256];
    int n = blockIdx.x * 256 + threadIdx.x;
    int c = blockIdx.y;
    int v0 = c * CHUNK;
    int v1 = min(V_N, v0 + CHUNK);

    double px = (double)pts[n*6+0], py = (double)pts[n*6+1], pz = (double)pts[n*6+2];
    double pp = px*px + py*py + pz*pz;
    double best = 1e300; int bi = 0x7fffffff;

    for (int vb = v0; vb < v1; vb += 256) {
        int t = vb + threadIdx.x;
        if (t < v1) {
            sx[threadIdx.x] = keyp[t*3+0];
            sy[threadIdx.x] = keyp[t*3+1];
            sz[threadIdx.x] = keyp[t*3+2];
        }
        __syncthreads();
        int lim = min(256, v1 - vb);
        for (int i = 0; i < lim; ++i) {
            double kx = (double)sx[i], ky = (double)sy[i], kz = (double)sz[i];
            double d = pp - 2.0*(px*kx + py*ky + pz*kz) + (kx*kx + ky*ky + kz*kz);
            if (d < best) { best = d; bi = vb + i; }
        }
        __syncthreads();
    }
    pd[(size_t)n*NCHUNK + c] = best;
    pi[(size_t)n*NCHUNK + c] = bi;
}

__global__ __launch_bounds__(256) void knn_reduce_kernel(
    const double* __restrict__ pd, const int* __restrict__ pi, int* __restrict__ knn)
{
    int n = blockIdx.x * 256 + threadIdx.x;
    double best = 1e300; int bi = 0x7fffffff;
#pragma unroll
    for (int c = 0; c < NCHUNK; ++c) {
        double d = pd[(size_t)n*NCHUNK + c];
        int    i = pi[(size_t)n*NCHUNK + c];
        if (d < best || (d == best && i < bi)) { best = d; bi = i; }
    }
    knn[n] = bi;
}

// ---------------- features: X row (700) + direction posenc tail (27) ----------------
__global__ __launch_bounds__(256) void feat_kernel(
    const float* __restrict__ pts, const float* __restrict__ keyp,
    const int* __restrict__ neigh, const float* __restrict__ restp,
    const float* __restrict__ latent, const float* __restrict__ rinv,
    const int* __restrict__ knn, float* __restrict__ X, float* __restrict__ out)
{
    int w = threadIdx.x >> 6;       // wave within block (0..3)
    int lane = threadIdx.x & 63;
    int n = blockIdx.x * 4 + w;     // point id

    __shared__ float s_vf[4][28];
    __shared__ int   s_vi[4][8];
    __shared__ float s_dir[4][4];

    int k = knn[n];
    float px = pts[n*6+0], py = pts[n*6+1], pz = pts[n*6+2];

    if (lane < 7) {
        int v = neigh[k*7 + lane];
        s_vi[w][lane] = v;
        float dx = px - keyp[v*3+0];
        float dy = py - keyp[v*3+1];
        float dz = pz - keyp[v*3+2];
        s_vf[w][21 + lane] = sqrtf(dx*dx + dy*dy + dz*dz);
    }
    if (lane == 7) {
        float dx = px - keyp[k*3+0];
        float dy = py - keyp[k*3+1];
        float dz = pz - keyp[k*3+2];
        const float* R = &rinv[k*9];
        float d0 = R[0]*dx + R[1]*dy + R[2]*dz;
        float d1 = R[3]*dx + R[4]*dy + R[5]*dz;
        float d2 = R[6]*dx + R[7]*dy + R[8]*dz;
        float nrm = fmaxf(sqrtf(d0*d0 + d1*d1 + d2*d2), 1e-12f);
        s_dir[w][0] = d0/nrm; s_dir[w][1] = d1/nrm; s_dir[w][2] = d2/nrm;
    }
    __syncthreads();
    if (lane < 21) {
        s_vf[w][lane] = restp[s_vi[w][lane/3]*3 + (lane%3)];
    }
    __syncthreads();

    // output tail: [dir(3), sin(dir_d * 2^f) f-major (12), cos (12)]
    if (lane < 27) {
        float val;
        if (lane < 3) val = s_dir[w][lane];
        else if (lane < 15) { int t = lane - 3;  val = sinf(s_dir[w][t%3] * (float)(1 << (t/3))); }
        else                { int t = lane - 15; val = cosf(s_dir[w][t%3] * (float)(1 << (t/3))); }
        out[(size_t)n*D_OUT + 256 + lane] = val;
    }

    // X row: [vfeat(28), sin(vf_d*2^f) f-major (280), cos (280), lfeat(112)]
    for (int i = lane; i < D_IN; i += 64) {
        float val;
        if (i < 28) {
            val = s_vf[w][i];
        } else if (i < 308) {
            int t = i - 28;  val = sinf(s_vf[w][t%28] * (float)(1 << (t/28)));
        } else if (i < 588) {
            int t = i - 308; val = cosf(s_vf[w][t%28] * (float)(1 << (t/28)));
        } else {
            int t = i - 588; val = latent[s_vi[w][t >> 4]*16 + (t & 15)];
        }
        X[(size_t)n*D_IN + i] = val;
    }
}

// ---------------- fp32 tiled GEMM: C = [relu](A @ W + b) ----------------
// A: N x K (lda), W: K x 256 row-major, C: N x ldc (writes 64x64 tile)
__global__ __launch_bounds__(256) void gemm_kernel(
    const float* __restrict__ A, int lda,
    const float* __restrict__ W, const float* __restrict__ bias,
    float* __restrict__ C, int ldc, int K, int do_relu)
{
    __shared__ float As[16][68];   // [k][m], padded stride 68
    __shared__ float Ws[16][68];   // [k][n], padded stride 68

    int tid = threadIdx.x;
    int bm = blockIdx.x * 64;
    int bn = blockIdx.y * 64;
    int tx = tid & 15, ty = tid >> 4;

    int arow = tid >> 2;           // 0..63
    int aks  = (tid & 3) << 2;     // 0,4,8,12
    int wk   = tid >> 4;           // 0..15
    int wn   = (tid & 15) << 2;    // 0..60

    float acc[4][4] = {};

    for (int k0 = 0; k0 < K; k0 += 16) {
        if (k0 + 16 <= K) {
            float4 av = *(const float4*)&A[(size_t)(bm + arow)*lda + k0 + aks];
            As[aks+0][arow] = av.x; As[aks+1][arow] = av.y;
            As[aks+2][arow] = av.z; As[aks+3][arow] = av.w;
            *(float4*)&Ws[wk][wn] = *(const float4*)&W[(size_t)(k0 + wk)*256 + bn + wn];
        } else {
#pragma unroll
            for (int j = 0; j < 4; ++j) {
                int kk = k0 + aks + j;
                As[aks+j][arow] = (kk < K) ? A[(size_t)(bm + arow)*lda + kk] : 0.0f;
            }
            if (k0 + wk < K) {
                *(float4*)&Ws[wk][wn] = *(const float4*)&W[(size_t)(k0 + wk)*256 + bn + wn];
            } else {
                Ws[wk][wn+0] = 0.0f; Ws[wk][wn+1] = 0.0f;
                Ws[wk][wn+2] = 0.0f; Ws[wk][wn+3] = 0.0f;
            }
        }
        __syncthreads();
#pragma unroll
        for (int kk = 0; kk < 16; ++kk) {
            float4 a = *(const float4*)&As[kk][ty << 2];
            float4 b = *(const float4*)&Ws[kk][tx << 2];
            acc[0][0] += a.x*b.x; acc[0][1] += a.x*b.y; acc[0][2] += a.x*b.z; acc[0][3] += a.x*b.w;
            acc[1][0] += a.y*b.x; acc[1][1] += a.y*b.y; acc[1][2] += a.y*b.z; acc[1][3] += a.y*b.w;
            acc[2][0] += a.z*b.x; acc[2][1] += a.z*b.y; acc[2][2] += a.z*b.z; acc[2][3] += a.z*b.w;
            acc[3][0] += a.w*b.x; acc[3][1] += a.w*b.y; acc[3][2] += a.w*b.z; acc[3][3] += a.w*b.w;
        }
        __syncthreads();
    }

#pragma unroll
    for (int i = 0; i < 4; ++i) {
        int row = bm + (ty << 2) + i;
#pragma unroll
        for (int j = 0; j < 4; ++j) {
            int col = bn + (tx << 2) + j;
            float val = acc[i][j] + bias[col];
            if (do_relu) val = fmaxf(val, 0.0f);
            C[(size_t)row*ldc + col] = val;
        }
    }
}

extern "C" void kernel_launch(void* const* d_in, const int* in_sizes, int n_in,
                              void* d_out, int out_size, void* d_ws, size_t ws_size,
                              hipStream_t stream) {
    const float* pts    = (const float*)d_in[0];
    const float* keyp   = (const float*)d_in[1];
    const float* trans  = (const float*)d_in[2];
    const int*   neigh  = (const int*)d_in[3];
    const float* restp  = (const float*)d_in[4];
    const float* latent = (const float*)d_in[5];
    const float* W1     = (const float*)d_in[6];
    const float* b1     = (const float*)d_in[7];
    const float* W2     = (const float*)d_in[8];
    const float* b2     = (const float*)d_in[9];
    const float* W3     = (const float*)d_in[10];
    const float* b3     = (const float*)d_in[11];
    float* out = (float*)d_out;

    float*  wsf  = (float*)d_ws;
    float*  rinv = wsf + RINV_OFF;
    float*  kk2  = wsf + KK_OFF;
    int*    knn  = (int*)(wsf + KNN_OFF);
    double* pd   = (double*)(wsf + PD_OFF);
    int*    pi   = (int*)(wsf + PI_OFF);
    float*  X    = wsf + X_OFF;
    float*  H1   = wsf + H1_OFF;
    float*  H2   = wsf + H2_OFF;

    prep_kernel<<<(V_N + 255)/256, 256, 0, stream>>>(trans, keyp, rinv, kk2);
    knn_part_kernel<<<dim3(N_PTS/256, NCHUNK), 256, 0, stream>>>(pts, keyp, pd, pi);
    knn_reduce_kernel<<<N_PTS/256, 256, 0, stream>>>(pd, pi, knn);
    feat_kernel<<<N_PTS/4, 256, 0, stream>>>(pts, keyp, neigh, restp, latent, rinv, knn, X, out);

    gemm_kernel<<<dim3(N_PTS/64, 4), 256, 0, stream>>>(X,  D_IN,  W1, b1, H1,  256, D_IN,  1);
    gemm_kernel<<<dim3(N_PTS/64, 4), 256, 0, stream>>>(H1, D_HID, W2, b2, H2,  256, D_HID, 1);
    gemm_kernel<<<dim3(N_PTS/64, 4), 256, 0, stream>>>(H2, D_HID, W3, b3, out, D_OUT, D_HID, 0);
}

// Round 2
// 213.884 us; speedup vs baseline: 1.4814x; 1.4814x over previous
//
#include <hip/hip_runtime.h>
#include <hip/hip_bf16.h>
#include <math.h>

#define V_N   6890
#define N_PTS 16384
#define D_IN  700
#define D_INP 704      // padded K for GEMM1
#define D_HID 256
#define D_OUT 283
#define NCHUNK 8
#define CHUNK  862     // ceil(6890/8)

// ws layout (float units; all 16B aligned)
#define RINV_OFF 0              // 62016
#define KNN_OFF  62016          // 16384 ints
#define PD_OFF   78400          // 16384*8 doubles = 262144 floats
#define PI_OFF   340544         // 16384*8 ints = 131072 floats
#define WT1_OFF  471616         // 256*704 bf16 = 90112 floats
#define WT2_OFF  561728         // 256*256 bf16 = 32768 floats
#define WT3_OFF  594496         // 32768 floats
#define X_OFF    627264         // 16384*704 bf16 = 5767168 floats
#define H1_OFF   6394432        // 16384*256 bf16 = 2097152 floats
#define H2_OFF   8491584        // 2097152 floats
// end ~10.6M floats = 42.4 MB

typedef __attribute__((ext_vector_type(8))) short short8;
typedef __attribute__((ext_vector_type(4))) float f32x4;

__device__ __forceinline__ unsigned short f2bf(float f) {
    unsigned int u = __builtin_bit_cast(unsigned int, f);
    u += 0x7fffu + ((u >> 16) & 1u);   // RNE
    return (unsigned short)(u >> 16);
}

__device__ __forceinline__ void glds16(const void* g, void* l) {
    __builtin_amdgcn_global_load_lds(
        (const __attribute__((address_space(1))) void*)g,
        (__attribute__((address_space(3))) void*)l, 16, 0, 0);
}

// ---------------- prep: per-vertex inv(4x4)[:3,:3] ----------------
__global__ __launch_bounds__(256) void prep_kernel(
    const float* __restrict__ trans, float* __restrict__ rinv)
{
    int v = blockIdx.x * 256 + threadIdx.x;
    if (v >= V_N) return;
    float m[16];
#pragma unroll
    for (int i = 0; i < 16; ++i) m[i] = trans[i * V_N + v];

    float i0  =  m[5]*m[10]*m[15] - m[5]*m[11]*m[14] - m[9]*m[6]*m[15] + m[9]*m[7]*m[14] + m[13]*m[6]*m[11] - m[13]*m[7]*m[10];
    float i4  = -m[4]*m[10]*m[15] + m[4]*m[11]*m[14] + m[8]*m[6]*m[15] - m[8]*m[7]*m[14] - m[12]*m[6]*m[11] + m[12]*m[7]*m[10];
    float i8  =  m[4]*m[9]*m[15]  - m[4]*m[11]*m[13] - m[8]*m[5]*m[15] + m[8]*m[7]*m[13] + m[12]*m[5]*m[11] - m[12]*m[7]*m[9];
    float i12 = -m[4]*m[9]*m[14]  + m[4]*m[10]*m[13] + m[8]*m[5]*m[14] - m[8]*m[6]*m[13] - m[12]*m[5]*m[10] + m[12]*m[6]*m[9];
    float i1  = -m[1]*m[10]*m[15] + m[1]*m[11]*m[14] + m[9]*m[2]*m[15] - m[9]*m[3]*m[14] - m[13]*m[2]*m[11] + m[13]*m[3]*m[10];
    float i5  =  m[0]*m[10]*m[15] - m[0]*m[11]*m[14] - m[8]*m[2]*m[15] + m[8]*m[3]*m[14] + m[12]*m[2]*m[11] - m[12]*m[3]*m[10];
    float i9  = -m[0]*m[9]*m[15]  + m[0]*m[11]*m[13] + m[8]*m[1]*m[15] - m[8]*m[3]*m[13] - m[12]*m[1]*m[11] + m[12]*m[3]*m[9];
    float i2  =  m[1]*m[6]*m[15]  - m[1]*m[7]*m[14]  - m[5]*m[2]*m[15] + m[5]*m[3]*m[14] + m[13]*m[2]*m[7]  - m[13]*m[3]*m[6];
    float i6  = -m[0]*m[6]*m[15]  + m[0]*m[7]*m[14]  + m[4]*m[2]*m[15] - m[4]*m[3]*m[14] - m[12]*m[2]*m[7]  + m[12]*m[3]*m[6];
    float i10 =  m[0]*m[5]*m[15]  - m[0]*m[7]*m[13]  - m[4]*m[1]*m[15] + m[4]*m[3]*m[13] + m[12]*m[1]*m[7]  - m[12]*m[3]*m[5];

    float det = m[0]*i0 + m[1]*i4 + m[2]*i8 + m[3]*i12;
    float id = 1.0f / det;
    rinv[v*9+0] = i0*id;  rinv[v*9+1] = i1*id;  rinv[v*9+2] = i2*id;
    rinv[v*9+3] = i4*id;  rinv[v*9+4] = i5*id;  rinv[v*9+5] = i6*id;
    rinv[v*9+6] = i8*id;  rinv[v*9+7] = i9*id;  rinv[v*9+8] = i10*id;
}

// ---------------- weight convert: fp32 W[k][n] -> bf16 Wt[n][k] (padded) ----------------
__global__ __launch_bounds__(256) void wconv_kernel(
    const float* __restrict__ W1, const float* __restrict__ W2,
    const float* __restrict__ W3, unsigned short* __restrict__ wt1,
    unsigned short* __restrict__ wt2, unsigned short* __restrict__ wt3)
{
    int idx = blockIdx.x * 256 + threadIdx.x;
    const int N1 = 256 * D_INP;          // 180224
    const int N2 = 256 * 256;            // 65536
    if (idx < N1) {
        int n = idx / D_INP, k = idx - n * D_INP;
        float v = (k < D_IN) ? W1[k * 256 + n] : 0.0f;
        wt1[n * D_INP + k] = f2bf(v);
    } else if (idx < N1 + N2) {
        int t = idx - N1;
        int n = t >> 8, k = t & 255;
        wt2[n * 256 + k] = f2bf(W2[k * 256 + n]);
    } else if (idx < N1 + 2 * N2) {
        int t = idx - N1 - N2;
        int n = t >> 8, k = t & 255;
        wt3[n * 256 + k] = f2bf(W3[k * 256 + n]);
    }
}

// ---------------- KNN: partial argmin over a V-chunk (fp64 distances) ----------------
__global__ __launch_bounds__(256) void knn_part_kernel(
    const float* __restrict__ pts, const float* __restrict__ keyp,
    double* __restrict__ pd, int* __restrict__ pi)
{
    __shared__ float sx[256], sy[256], sz[256];
    int n = blockIdx.x * 256 + threadIdx.x;
    int c = blockIdx.y;
    int v0 = c * CHUNK;
    int v1 = min(V_N, v0 + CHUNK);

    double px = (double)pts[n*6+0], py = (double)pts[n*6+1], pz = (double)pts[n*6+2];
    double pp = px*px + py*py + pz*pz;
    double best = 1e300; int bi = 0x7fffffff;

    for (int vb = v0; vb < v1; vb += 256) {
        int t = vb + threadIdx.x;
        if (t < v1) {
            sx[threadIdx.x] = keyp[t*3+0];
            sy[threadIdx.x] = keyp[t*3+1];
            sz[threadIdx.x] = keyp[t*3+2];
        }
        __syncthreads();
        int lim = min(256, v1 - vb);
        for (int i = 0; i < lim; ++i) {
            double kx = (double)sx[i], ky = (double)sy[i], kz = (double)sz[i];
            double d = pp - 2.0*(px*kx + py*ky + pz*kz) + (kx*kx + ky*ky + kz*kz);
            if (d < best) { best = d; bi = vb + i; }
        }
        __syncthreads();
    }
    pd[(size_t)n*NCHUNK + c] = best;
    pi[(size_t)n*NCHUNK + c] = bi;
}

__global__ __launch_bounds__(256) void knn_reduce_kernel(
    const double* __restrict__ pd, const int* __restrict__ pi, int* __restrict__ knn)
{
    int n = blockIdx.x * 256 + threadIdx.x;
    double best = 1e300; int bi = 0x7fffffff;
#pragma unroll
    for (int c = 0; c < NCHUNK; ++c) {
        double d = pd[(size_t)n*NCHUNK + c];
        int    i = pi[(size_t)n*NCHUNK + c];
        if (d < best || (d == best && i < bi)) { best = d; bi = i; }
    }
    knn[n] = bi;
}

// ---------------- features: X row (bf16, 704 padded) + direction posenc tail ----------------
__global__ __launch_bounds__(256) void feat_kernel(
    const float* __restrict__ pts, const float* __restrict__ keyp,
    const int* __restrict__ neigh, const float* __restrict__ restp,
    const float* __restrict__ latent, const float* __restrict__ rinv,
    const int* __restrict__ knn, unsigned short* __restrict__ X,
    float* __restrict__ out)
{
    int w = threadIdx.x >> 6;       // wave in block
    int lane = threadIdx.x & 63;
    int n = blockIdx.x * 4 + w;     // point id

    __shared__ float s_vf[4][28];
    __shared__ int   s_vi[4][8];
    __shared__ float s_dir[4][4];

    int k = knn[n];
    float px = pts[n*6+0], py = pts[n*6+1], pz = pts[n*6+2];

    if (lane < 7) {
        int v = neigh[k*7 + lane];
        s_vi[w][lane] = v;
        float dx = px - keyp[v*3+0];
        float dy = py - keyp[v*3+1];
        float dz = pz - keyp[v*3+2];
        s_vf[w][21 + lane] = sqrtf(dx*dx + dy*dy + dz*dz);
    }
    if (lane == 7) {
        float dx = px - keyp[k*3+0];
        float dy = py - keyp[k*3+1];
        float dz = pz - keyp[k*3+2];
        const float* R = &rinv[k*9];
        float d0 = R[0]*dx + R[1]*dy + R[2]*dz;
        float d1 = R[3]*dx + R[4]*dy + R[5]*dz;
        float d2 = R[6]*dx + R[7]*dy + R[8]*dz;
        float nrm = fmaxf(sqrtf(d0*d0 + d1*d1 + d2*d2), 1e-12f);
        s_dir[w][0] = d0/nrm; s_dir[w][1] = d1/nrm; s_dir[w][2] = d2/nrm;
    }
    __syncthreads();
    if (lane < 21) {
        s_vf[w][lane] = restp[s_vi[w][lane/3]*3 + (lane%3)];
    }
    __syncthreads();

    // output tail (fp32): [dir(3), sin f-major (12), cos (12)]
    if (lane < 27) {
        float val;
        if (lane < 3) val = s_dir[w][lane];
        else if (lane < 15) { int t = lane - 3;  val = sinf(s_dir[w][t%3] * (float)(1 << (t/3))); }
        else                { int t = lane - 15; val = cosf(s_dir[w][t%3] * (float)(1 << (t/3))); }
        out[(size_t)n*D_OUT + 256 + lane] = val;
    }

    // X row bf16: [vfeat(28), sin (280), cos (280), lfeat(112), pad(4)=0]
    for (int i = lane; i < D_INP; i += 64) {
        float val;
        if (i < 28) {
            val = s_vf[w][i];
        } else if (i < 308) {
            int t = i - 28;  val = sinf(s_vf[w][t%28] * (float)(1 << (t/28)));
        } else if (i < 588) {
            int t = i - 308; val = cosf(s_vf[w][t%28] * (float)(1 << (t/28)));
        } else if (i < 700) {
            int t = i - 588; val = latent[s_vi[w][t >> 4]*16 + (t & 15)];
        } else {
            val = 0.0f;
        }
        X[(size_t)n*D_INP + i] = f2bf(val);
    }
}

// ---------------- bf16 MFMA GEMM: C = [relu](A @ Wt^T + b) ----------------
// A: N x lda bf16 row-major; Wt: 256 x ldw bf16 (output-col-major rows, k contig)
// block: 512 thr = 8 waves; tile BM=128 x BN=128, BK=32
// wave w: rows (w>>2)*64, cols (w&3)*32 -> 4x2 frags of 16x16
__global__ __launch_bounds__(512) void mfma_gemm(
    const unsigned short* __restrict__ A, int lda,
    const unsigned short* __restrict__ Wt, int ldw,
    const float* __restrict__ bias,
    void* __restrict__ Cout, int ldc, int K, int relu_bf16out)
{
    __shared__ unsigned short As[128 * 32];   // [m][k], 8KB
    __shared__ unsigned short Bs[128 * 32];   // [n][k], 8KB

    int t = threadIdx.x;
    int bm = blockIdx.x * 128;
    int bn = blockIdx.y * 128;

    int l = t & 63, w = t >> 6;
    int mbase = (w >> 2) * 64;
    int nbase = (w & 3) * 32;
    int lrow = l & 15;
    int lk = (l >> 4) * 8;

    // staging addresses: thread t covers row t>>2, 16B chunk t&3
    const char* gA0 = (const char*)(A + (size_t)(bm + (t >> 2)) * lda) + (t & 3) * 16;
    const char* gB0 = (const char*)(Wt + (size_t)(bn + (t >> 2)) * ldw) + (t & 3) * 16;
    char* lA = (char*)As + t * 16;
    char* lB = (char*)Bs + t * 16;

    f32x4 acc[4][2];
#pragma unroll
    for (int i = 0; i < 4; ++i)
#pragma unroll
        for (int j = 0; j < 2; ++j) acc[i][j] = {0.f, 0.f, 0.f, 0.f};

    for (int k0 = 0; k0 < K; k0 += 32) {
        glds16(gA0 + (size_t)k0 * 2, lA);
        glds16(gB0 + (size_t)k0 * 2, lB);
        __syncthreads();   // drains vmcnt (glds) before reads

        short8 af[4], bf[2];
#pragma unroll
        for (int mi = 0; mi < 4; ++mi)
            af[mi] = *(const short8*)&As[(mbase + mi * 16 + lrow) * 32 + lk];
#pragma unroll
        for (int ni = 0; ni < 2; ++ni)
            bf[ni] = *(const short8*)&Bs[(nbase + ni * 16 + lrow) * 32 + lk];

#pragma unroll
        for (int mi = 0; mi < 4; ++mi)
#pragma unroll
            for (int ni = 0; ni < 2; ++ni)
                acc[mi][ni] = __builtin_amdgcn_mfma_f32_16x16x32_bf16(
                    af[mi], bf[ni], acc[mi][ni], 0, 0, 0);
        __syncthreads();   // protect LDS before next stage
    }

    // epilogue: C/D layout col=lane&15, row=(lane>>4)*4+reg
#pragma unroll
    for (int mi = 0; mi < 4; ++mi) {
#pragma unroll
        for (int ni = 0; ni < 2; ++ni) {
            int col = bn + nbase + ni * 16 + (l & 15);
            float bv = bias[col];
#pragma unroll
            for (int r = 0; r < 4; ++r) {
                int row = bm + mbase + mi * 16 + (l >> 4) * 4 + r;
                float val = acc[mi][ni][r] + bv;
                if (relu_bf16out) {
                    val = fmaxf(val, 0.0f);
                    ((unsigned short*)Cout)[(size_t)row * ldc + col] = f2bf(val);
                } else {
                    ((float*)Cout)[(size_t)row * ldc + col] = val;
                }
            }
        }
    }
}

extern "C" void kernel_launch(void* const* d_in, const int* in_sizes, int n_in,
                              void* d_out, int out_size, void* d_ws, size_t ws_size,
                              hipStream_t stream) {
    const float* pts    = (const float*)d_in[0];
    const float* keyp   = (const float*)d_in[1];
    const float* trans  = (const float*)d_in[2];
    const int*   neigh  = (const int*)d_in[3];
    const float* restp  = (const float*)d_in[4];
    const float* latent = (const float*)d_in[5];
    const float* W1     = (const float*)d_in[6];
    const float* b1     = (const float*)d_in[7];
    const float* W2     = (const float*)d_in[8];
    const float* b2     = (const float*)d_in[9];
    const float* W3     = (const float*)d_in[10];
    const float* b3     = (const float*)d_in[11];
    float* out = (float*)d_out;

    float* wsf = (float*)d_ws;
    float*          rinv = wsf + RINV_OFF;
    int*            knn  = (int*)(wsf + KNN_OFF);
    double*         pd   = (double*)(wsf + PD_OFF);
    int*            pi   = (int*)(wsf + PI_OFF);
    unsigned short* wt1  = (unsigned short*)(wsf + WT1_OFF);
    unsigned short* wt2  = (unsigned short*)(wsf + WT2_OFF);
    unsigned short* wt3  = (unsigned short*)(wsf + WT3_OFF);
    unsigned short* X    = (unsigned short*)(wsf + X_OFF);
    unsigned short* H1   = (unsigned short*)(wsf + H1_OFF);
    unsigned short* H2   = (unsigned short*)(wsf + H2_OFF);

    prep_kernel<<<(V_N + 255)/256, 256, 0, stream>>>(trans, rinv);
    wconv_kernel<<<(256*D_INP + 2*256*256 + 255)/256, 256, 0, stream>>>(
        W1, W2, W3, wt1, wt2, wt3);
    knn_part_kernel<<<dim3(N_PTS/256, NCHUNK), 256, 0, stream>>>(pts, keyp, pd, pi);
    knn_reduce_kernel<<<N_PTS/256, 256, 0, stream>>>(pd, pi, knn);
    feat_kernel<<<N_PTS/4, 256, 0, stream>>>(pts, keyp, neigh, restp, latent, rinv, knn, X, out);

    mfma_gemm<<<dim3(N_PTS/128, 2), 512, 0, stream>>>(X,  D_INP, wt1, D_INP, b1, H1,  256, D_INP, 1);
    mfma_gemm<<<dim3(N_PTS/128, 2), 512, 0, stream>>>(H1, D_HID, wt2, D_HID, b2, H2,  256, D_HID, 1);
    mfma_gemm<<<dim3(N_PTS/128, 2), 512, 0, stream>>>(H2, D_HID, wt3, D_HID, b3, out, D_OUT, D_HID, 0);
}